// Round 11
// baseline (134.452 us; speedup 1.0000x reference)
//
#include <hip/hip_runtime.h>
#include <math.h>

// CPC loss, MI355X. B=16 T=512 D=256, horizons {1,5,21}, 128 negatives, temp 0.07.
// ws: [0,4MB) az f16 | [4MB,+2MB) ani int8 | [6MB,+384KB) Wh f16 |
//     [6.375MB,+12MB) zp f16 | [18.375MB,+24KB) partials f32
constexpr int Bc = 16, Tc = 512, Dc = 256, NNEGc = 128, BTc = Bc * Tc;
constexpr float TEMP_INV = 1.0f / 0.07f;
constexpr float QSCALE = TEMP_INV / (127.0f * 127.0f);
constexpr float FMAXL = TEMP_INV;   // structural logit bound: |dot|<=~1 -> lg<=~14.3
constexpr int GX = 2043;            // k_loss grid.x = ceil(8176/4)
constexpr int NPART = 3 * GX;

typedef __attribute__((ext_vector_type(8))) short short8;
typedef __attribute__((ext_vector_type(4))) float f32x4;
typedef __attribute__((ext_vector_type(4))) _Float16 f16x4;
typedef __attribute__((ext_vector_type(2))) _Float16 h2;

struct HP { int L, N, kh; float scale; long long nxOff; };
struct HP3 { HP h[3]; };

__device__ inline unsigned packh2(float a, float b) {
    h2 p = {(_Float16)a, (_Float16)b};
    return __builtin_bit_cast(unsigned, p);
}
__device__ inline float dot2(unsigned a, unsigned b, float c) {
#if __has_builtin(__builtin_amdgcn_fdot2)
    return __builtin_amdgcn_fdot2(__builtin_bit_cast(h2, a), __builtin_bit_cast(h2, b), c, false);
#else
    h2 x = __builtin_bit_cast(h2, a), y = __builtin_bit_cast(h2, b);
    return c + (float)x.x * (float)y.x + (float)x.y * (float)y.y;
#endif
}
__device__ inline int sdot4(unsigned a, unsigned b, int c) {
#if __has_builtin(__builtin_amdgcn_sdot4)
    return __builtin_amdgcn_sdot4((int)a, (int)b, c, false);
#else
    c += (int)(char)(a) * (int)(char)(b);
    c += (int)(char)(a >> 8) * (int)(char)(b >> 8);
    c += (int)(char)(a >> 16) * (int)(char)(b >> 16);
    c += (int)(char)(a >> 24) * (int)(char)(b >> 24);
    return c;
#endif
}
__device__ inline unsigned q4i8(float a, float b, float c, float d) {
    int qa = (int)rintf(a * 127.0f), qb = (int)rintf(b * 127.0f);
    int qc = (int)rintf(c * 127.0f), qd = (int)rintf(d * 127.0f);
    return (qa & 0xff) | ((qb & 0xff) << 8) | ((qc & 0xff) << 16) | ((unsigned)qd << 24);
}

// Normalize all BT rows -> az (f16) + ani (int8); first 96 blocks convert W.
__global__ __launch_bounds__(256) void k_norm(const float* __restrict__ z,
                                              const float* __restrict__ preds,
                                              unsigned* __restrict__ az,
                                              unsigned* __restrict__ ani,
                                              unsigned* __restrict__ Wh) {
    if (blockIdx.x < 96) {
        int base = blockIdx.x * 2048 + threadIdx.x * 8;
        float4 w0 = reinterpret_cast<const float4*>(preds + base)[0];
        float4 w1 = reinterpret_cast<const float4*>(preds + base)[1];
        uint4 o;
        o.x = packh2(w0.x, w0.y); o.y = packh2(w0.z, w0.w);
        o.z = packh2(w1.x, w1.y); o.w = packh2(w1.z, w1.w);
        reinterpret_cast<uint4*>(Wh)[blockIdx.x * 256 + threadIdx.x] = o;
    }
    int wid = threadIdx.x >> 6, lane = threadIdx.x & 63;
    int row = blockIdx.x * 4 + wid;
    float4 v = reinterpret_cast<const float4*>(z)[row * 64 + lane];
    float s = v.x * v.x + v.y * v.y + v.z * v.z + v.w * v.w;
#pragma unroll
    for (int off = 32; off; off >>= 1) s += __shfl_xor(s, off, 64);
    float inv = 1.0f / fmaxf(sqrtf(s), 1e-12f);
    float a = v.x * inv, b = v.y * inv, c = v.z * inv, d = v.w * inv;
    reinterpret_cast<uint2*>(az)[row * 64 + lane] = make_uint2(packh2(a, b), packh2(c, d));
    ani[row * 64 + lane] = q4i8(a, b, c, d);
}

// LDS-tiled f16 MFMA GEMM, XOR-swizzled LDS. Block 64x64, K=256, 4 waves.
__global__ __launch_bounds__(256) void k_gemm(const unsigned* __restrict__ az,
                                              const unsigned* __restrict__ Wh,
                                              _Float16* __restrict__ zp) {
    __shared__ uint4 As[2048];
    __shared__ uint4 Bs[2048];
    int wave = threadIdx.x >> 6, lane = threadIdx.x & 63;
    int t = threadIdx.x;
    int m0 = blockIdx.x * 64, g0 = blockIdx.y * 64;
    const uint4* A4 = reinterpret_cast<const uint4*>(az) + (size_t)m0 * 32;
    const uint4* B4 = reinterpret_cast<const uint4*>(Wh) + (size_t)g0 * 32;
#pragma unroll
    for (int i = 0; i < 8; ++i) {
        int f = i * 256 + t;
        int r = f >> 5, c = f & 31;
        int sw = r * 32 + ((c ^ r) & 31);
        As[sw] = A4[f];
        Bs[sw] = B4[f];
    }
    __syncthreads();
    int mrow = lane & 15, kq = lane >> 4;
    f32x4 acc[4] = {f32x4{0,0,0,0}, f32x4{0,0,0,0}, f32x4{0,0,0,0}, f32x4{0,0,0,0}};
    int arow = wave * 16 + mrow;
#pragma unroll
    for (int kb = 0; kb < 8; ++kb) {
        int col = kb * 4 + kq;
        uint4 ua = As[arow * 32 + ((col ^ arow) & 31)];
        short8 a = __builtin_bit_cast(short8, ua);
#pragma unroll
        for (int nt = 0; nt < 4; ++nt) {
            int brow = nt * 16 + mrow;
            uint4 ub = Bs[brow * 32 + ((col ^ brow) & 31)];
            acc[nt] = __builtin_amdgcn_mfma_f32_16x16x32_f16(
                a, __builtin_bit_cast(short8, ub), acc[nt], 0, 0, 0);
        }
    }
#pragma unroll
    for (int nt = 0; nt < 4; ++nt) {
        int g = g0 + nt * 16 + mrow;
        int h = g >> 8, e = g & 255;
        _Float16* dst = zp + ((size_t)h * BTc + m0 + wave * 16 + kq * 4) * Dc + e;
#pragma unroll
        for (int r = 0; r < 4; ++r) dst[(size_t)r * Dc] = (_Float16)acc[nt][r];
    }
}

// One wave per row n. 16-LANE-CONTIGUOUS gather: pass p covers negatives
// j=p*4+g (g=lane>>4); 16 lanes x 16B = one 256B contiguous run per negative
// (4 runs/instr vs 16 in the quad layout). Fixed-max softmax (FM=1/temp).
// Double-buffered 4-pass prefetch. Per-block partial store.
__global__ __launch_bounds__(256, 4) void k_loss(const unsigned* __restrict__ az,
                                                 const unsigned* __restrict__ ani,
                                                 const _Float16* __restrict__ zp_base,
                                                 const int* __restrict__ nx_base,
                                                 float* __restrict__ partials,
                                                 HP3 P) {
    HP hp = P.h[blockIdx.y];
    __shared__ unsigned zq[4][64];
    __shared__ float partial[4];
    int wid = threadIdx.x >> 6, lane = threadIdx.x & 63;
    int g = lane >> 4, s = lane & 15;
    int n = blockIdx.x * 4 + wid;
    float contrib = 0.0f;
    if (n < hp.N) {
        const int* nx = nx_base + hp.nxOff + (size_t)n * NNEGc;
        int i1 = nx[lane], i2 = nx[lane + 64];
        const uint4* ni4 = reinterpret_cast<const uint4*>(ani);
#define IDX(p) __shfl(((p) < 16 ? i1 : i2), (((p) & 15) << 2) + g, 64)

        // setup (rides under the first prefetch): normalize z_pred, pos logit, zq
        int b = n / hp.L, l = n - b * hp.L;
        int row = b * Tc + l;
        f16x4 hv = reinterpret_cast<const f16x4*>(
                       zp_base + ((size_t)blockIdx.y * BTc + row) * Dc)[lane];
        uint2 pw = reinterpret_cast<const uint2*>(az + (size_t)(row + hp.kh) * 128)[lane];

        uint4 buf[2][4];
#pragma unroll
        for (int j = 0; j < 4; ++j) buf[0][j] = ni4[(size_t)IDX(j) * 16 + s];

        float4 v = make_float4((float)hv.x, (float)hv.y, (float)hv.z, (float)hv.w);
        float sq = v.x * v.x + v.y * v.y + v.z * v.z + v.w * v.w;
#pragma unroll
        for (int off = 32; off; off >>= 1) sq += __shfl_xor(sq, off, 64);
        float inv = 1.0f / fmaxf(sqrtf(sq), 1e-12f);
        v.x *= inv; v.y *= inv; v.z *= inv; v.w *= inv;
        zq[wid][lane] = q4i8(v.x, v.y, v.z, v.w);
        float pd = dot2(pw.y, packh2(v.z, v.w), dot2(pw.x, packh2(v.x, v.y), 0.0f));
#pragma unroll
        for (int off = 32; off; off >>= 1) pd += __shfl_xor(pd, off, 64);
        float pos = pd * TEMP_INV;
        uint4 zs = reinterpret_cast<const uint4*>(zq[wid])[s];  // own 16 dims

        float sl = 0.0f;
#pragma unroll
        for (int k = 0; k < 8; ++k) {
            int cur = k & 1, nxt = cur ^ 1;
            if (k < 7) {
#pragma unroll
                for (int j = 0; j < 4; ++j) {
                    int p = (k + 1) * 4 + j;
                    buf[nxt][j] = ni4[(size_t)IDX(p) * 16 + s];
                }
            }
#pragma unroll
            for (int j = 0; j < 4; ++j) {
                uint4 gl = buf[cur][j];
                int acc = 0;
                acc = sdot4(gl.x, zs.x, acc);
                acc = sdot4(gl.y, zs.y, acc);
                acc = sdot4(gl.z, zs.z, acc);
                acc = sdot4(gl.w, zs.w, acc);
                acc += __shfl_xor(acc, 1, 64);
                acc += __shfl_xor(acc, 2, 64);
                acc += __shfl_xor(acc, 4, 64);
                acc += __shfl_xor(acc, 8, 64);
                sl += __expf((float)acc * QSCALE - FMAXL);
            }
        }
#undef IDX
        // sl identical within a 16-lane group; sum the 4 groups
        sl += __shfl_xor(sl, 16, 64);
        sl += __shfl_xor(sl, 32, 64);
        float S = sl + __expf(pos - FMAXL);
        contrib = (FMAXL + __logf(S) - pos) * hp.scale;
    }
    if (lane == 0) partial[wid] = contrib;
    __syncthreads();
    if (threadIdx.x == 0)
        partials[blockIdx.y * GX + blockIdx.x] =
            partial[0] + partial[1] + partial[2] + partial[3];
}

// Single-block deterministic reduction of NPART partials -> out[0].
__global__ __launch_bounds__(256) void k_final(const float* __restrict__ partials,
                                               float* __restrict__ out) {
    __shared__ float ws[4];
    int wid = threadIdx.x >> 6, lane = threadIdx.x & 63;
    float s = 0.0f;
    for (int i = threadIdx.x; i < NPART; i += 256) s += partials[i];
#pragma unroll
    for (int off = 32; off; off >>= 1) s += __shfl_xor(s, off, 64);
    if (lane == 0) ws[wid] = s;
    __syncthreads();
    if (threadIdx.x == 0) out[0] = ws[0] + ws[1] + ws[2] + ws[3];
}

extern "C" void kernel_launch(void* const* d_in, const int* in_sizes, int n_in,
                              void* d_out, int out_size, void* d_ws, size_t ws_size,
                              hipStream_t stream) {
    const float* z     = (const float*)d_in[0];
    const float* preds = (const float*)d_in[1];
    const int*   nidx  = (const int*)d_in[2];
    float* out = (float*)d_out;

    unsigned* az   = (unsigned*)d_ws;                                // 4 MB
    unsigned* ani  = (unsigned*)((char*)d_ws + (size_t)4194304);     // 2 MB
    unsigned* Wh   = (unsigned*)((char*)d_ws + (size_t)6291456);     // 384 KB
    _Float16* zp   = (_Float16*)((char*)d_ws + (size_t)6684672);     // 12 MB
    float*    part = (float*)((char*)d_ws + (size_t)19267584);       // 24 KB

    const int ks[3] = {1, 5, 21};
    double rw[3] = {1.0, 1.0 / sqrt(5.0), 1.0 / sqrt(21.0)};
    double tot = rw[0] + rw[1] + rw[2];

    HP3 P;
    for (int i = 0; i < 3; ++i) {
        int L = Tc - ks[i], N = Bc * L;
        P.h[i].L = L; P.h[i].N = N; P.h[i].kh = ks[i];
        P.h[i].scale = (float)(rw[i] / tot / (double)N);
        P.h[i].nxOff = (long long)i * BTc * NNEGc;
    }

    k_norm<<<BTc / 4, 256, 0, stream>>>(z, preds, az, ani, Wh);
    k_gemm<<<dim3(BTc / 64, (3 * Dc) / 64), 256, 0, stream>>>(az, Wh, zp);
    k_loss<<<dim3(GX, 3), 256, 0, stream>>>(az, ani, zp, nidx, part, P);
    k_final<<<1, 256, 0, stream>>>(part, out);
}

// Round 13
// 117.114 us; speedup vs baseline: 1.1480x; 1.1480x over previous
//
#include <hip/hip_runtime.h>
#include <math.h>

// CPC loss, MI355X. B=16 T=512 D=256, horizons {1,5,21}, 128 negatives, temp 0.07.
// ws: [0,4MB) az f16 | [4MB,+2MB) ani int8 | [6MB,+384KB) Wh f16 |
//     [6.375MB,+12MB) zp f16 | [18.375MB,+24KB) partials f32
constexpr int Bc = 16, Tc = 512, Dc = 256, NNEGc = 128, BTc = Bc * Tc;
constexpr float TEMP_INV = 1.0f / 0.07f;
constexpr float QSCALE = TEMP_INV / (127.0f * 127.0f);
constexpr float FMAXL = TEMP_INV;   // structural logit bound (|dot|<=~1)
constexpr int GX = 2043;            // k_loss grid.x = ceil(8176/4)
constexpr int NPART = 3 * GX;

typedef __attribute__((ext_vector_type(8))) short short8;
typedef __attribute__((ext_vector_type(4))) float f32x4;
typedef __attribute__((ext_vector_type(4))) _Float16 f16x4;
typedef __attribute__((ext_vector_type(2))) _Float16 h2;

struct HP { int L, N, kh; float scale; long long nxOff; };
struct HP3 { HP h[3]; };

__device__ inline unsigned packh2(float a, float b) {
    h2 p = {(_Float16)a, (_Float16)b};
    return __builtin_bit_cast(unsigned, p);
}
__device__ inline float dot2(unsigned a, unsigned b, float c) {
#if __has_builtin(__builtin_amdgcn_fdot2)
    return __builtin_amdgcn_fdot2(__builtin_bit_cast(h2, a), __builtin_bit_cast(h2, b), c, false);
#else
    h2 x = __builtin_bit_cast(h2, a), y = __builtin_bit_cast(h2, b);
    return c + (float)x.x * (float)y.x + (float)x.y * (float)y.y;
#endif
}
__device__ inline int sdot4(unsigned a, unsigned b, int c) {
#if __has_builtin(__builtin_amdgcn_sdot4)
    return __builtin_amdgcn_sdot4((int)a, (int)b, c, false);
#else
    c += (int)(char)(a) * (int)(char)(b);
    c += (int)(char)(a >> 8) * (int)(char)(b >> 8);
    c += (int)(char)(a >> 16) * (int)(char)(b >> 16);
    c += (int)(char)(a >> 24) * (int)(char)(b >> 24);
    return c;
#endif
}
__device__ inline unsigned q4i8(float a, float b, float c, float d) {
    int qa = (int)rintf(a * 127.0f), qb = (int)rintf(b * 127.0f);
    int qc = (int)rintf(c * 127.0f), qd = (int)rintf(d * 127.0f);
    return (qa & 0xff) | ((qb & 0xff) << 8) | ((qc & 0xff) << 16) | ((unsigned)qd << 24);
}

// Normalize all BT rows -> az (f16) + ani (int8); first 96 blocks convert W.
__global__ __launch_bounds__(256) void k_norm(const float* __restrict__ z,
                                              const float* __restrict__ preds,
                                              unsigned* __restrict__ az,
                                              unsigned* __restrict__ ani,
                                              unsigned* __restrict__ Wh) {
    if (blockIdx.x < 96) {
        int base = blockIdx.x * 2048 + threadIdx.x * 8;
        float4 w0 = reinterpret_cast<const float4*>(preds + base)[0];
        float4 w1 = reinterpret_cast<const float4*>(preds + base)[1];
        uint4 o;
        o.x = packh2(w0.x, w0.y); o.y = packh2(w0.z, w0.w);
        o.z = packh2(w1.x, w1.y); o.w = packh2(w1.z, w1.w);
        reinterpret_cast<uint4*>(Wh)[blockIdx.x * 256 + threadIdx.x] = o;
    }
    int wid = threadIdx.x >> 6, lane = threadIdx.x & 63;
    int row = blockIdx.x * 4 + wid;
    float4 v = reinterpret_cast<const float4*>(z)[row * 64 + lane];
    float s = v.x * v.x + v.y * v.y + v.z * v.z + v.w * v.w;
#pragma unroll
    for (int off = 32; off; off >>= 1) s += __shfl_xor(s, off, 64);
    float inv = 1.0f / fmaxf(sqrtf(s), 1e-12f);
    float a = v.x * inv, b = v.y * inv, c = v.z * inv, d = v.w * inv;
    reinterpret_cast<uint2*>(az)[row * 64 + lane] = make_uint2(packh2(a, b), packh2(c, d));
    ani[row * 64 + lane] = q4i8(a, b, c, d);
}

// LDS-tiled f16 MFMA GEMM, XOR-swizzled LDS. Block 64x64, K=256, 4 waves.
__global__ __launch_bounds__(256) void k_gemm(const unsigned* __restrict__ az,
                                              const unsigned* __restrict__ Wh,
                                              _Float16* __restrict__ zp) {
    __shared__ uint4 As[2048];
    __shared__ uint4 Bs[2048];
    int wave = threadIdx.x >> 6, lane = threadIdx.x & 63;
    int t = threadIdx.x;
    int m0 = blockIdx.x * 64, g0 = blockIdx.y * 64;
    const uint4* A4 = reinterpret_cast<const uint4*>(az) + (size_t)m0 * 32;
    const uint4* B4 = reinterpret_cast<const uint4*>(Wh) + (size_t)g0 * 32;
#pragma unroll
    for (int i = 0; i < 8; ++i) {
        int f = i * 256 + t;
        int r = f >> 5, c = f & 31;
        int sw = r * 32 + ((c ^ r) & 31);
        As[sw] = A4[f];
        Bs[sw] = B4[f];
    }
    __syncthreads();
    int mrow = lane & 15, kq = lane >> 4;
    f32x4 acc[4] = {f32x4{0,0,0,0}, f32x4{0,0,0,0}, f32x4{0,0,0,0}, f32x4{0,0,0,0}};
    int arow = wave * 16 + mrow;
#pragma unroll
    for (int kb = 0; kb < 8; ++kb) {
        int col = kb * 4 + kq;
        uint4 ua = As[arow * 32 + ((col ^ arow) & 31)];
        short8 a = __builtin_bit_cast(short8, ua);
#pragma unroll
        for (int nt = 0; nt < 4; ++nt) {
            int brow = nt * 16 + mrow;
            uint4 ub = Bs[brow * 32 + ((col ^ brow) & 31)];
            acc[nt] = __builtin_amdgcn_mfma_f32_16x16x32_f16(
                a, __builtin_bit_cast(short8, ub), acc[nt], 0, 0, 0);
        }
    }
#pragma unroll
    for (int nt = 0; nt < 4; ++nt) {
        int g = g0 + nt * 16 + mrow;
        int h = g >> 8, e = g & 255;
        _Float16* dst = zp + ((size_t)h * BTc + m0 + wave * 16 + kq * 4) * Dc + e;
#pragma unroll
        for (int r = 0; r < 4; ++r) dst[(size_t)r * Dc] = (_Float16)acc[nt][r];
    }
}

// One wave per row n. 8-LANE-PER-NEGATIVE gather: pass p covers negatives
// j=p*8+g (g=lane>>3); 8 lanes x 16B = 128B-ALIGNED FULLY-CONSUMED lines
// (8 full lines per instr — minimal line touches). 16 passes x 2 loads,
// double-buffered. Fixed-max softmax. NOTE: cross-group butterfly (xor 8/16/32)
// sums ONE representative per group — no 1/8 factor (bug in prev round).
__global__ __launch_bounds__(256, 4) void k_loss(const unsigned* __restrict__ az,
                                                 const unsigned* __restrict__ ani,
                                                 const _Float16* __restrict__ zp_base,
                                                 const int* __restrict__ nx_base,
                                                 float* __restrict__ partials,
                                                 HP3 P) {
    HP hp = P.h[blockIdx.y];
    __shared__ unsigned zq[4][64];
    __shared__ float partial[4];
    int wid = threadIdx.x >> 6, lane = threadIdx.x & 63;
    int g = lane >> 3, s = lane & 7;
    int n = blockIdx.x * 4 + wid;
    float contrib = 0.0f;
    if (n < hp.N) {
        const int* nx = nx_base + hp.nxOff + (size_t)n * NNEGc;
        int i1 = nx[lane], i2 = nx[lane + 64];
        // all 16 per-pass indices up-front: pass p, group g -> negative p*8+g
        int idxp[16];
#pragma unroll
        for (int p = 0; p < 16; ++p)
            idxp[p] = __shfl(p < 8 ? i1 : i2, (p & 7) * 8 + g, 64);

        const uint4* ni4 = reinterpret_cast<const uint4*>(ani);
        uint4 buf[2][2];
        buf[0][0] = ni4[(size_t)idxp[0] * 16 + s];
        buf[0][1] = ni4[(size_t)idxp[0] * 16 + 8 + s];

        // setup rides under the first prefetch
        int b = n / hp.L, l = n - b * hp.L;
        int row = b * Tc + l;
        f16x4 hv = reinterpret_cast<const f16x4*>(
                       zp_base + ((size_t)blockIdx.y * BTc + row) * Dc)[lane];
        uint2 pw = reinterpret_cast<const uint2*>(az + (size_t)(row + hp.kh) * 128)[lane];
        float4 v = make_float4((float)hv.x, (float)hv.y, (float)hv.z, (float)hv.w);
        float sq = v.x * v.x + v.y * v.y + v.z * v.z + v.w * v.w;
#pragma unroll
        for (int off = 32; off; off >>= 1) sq += __shfl_xor(sq, off, 64);
        float inv = 1.0f / fmaxf(sqrtf(sq), 1e-12f);
        v.x *= inv; v.y *= inv; v.z *= inv; v.w *= inv;
        zq[wid][lane] = q4i8(v.x, v.y, v.z, v.w);
        float pd = dot2(pw.y, packh2(v.z, v.w), dot2(pw.x, packh2(v.x, v.y), 0.0f));
#pragma unroll
        for (int off = 32; off; off >>= 1) pd += __shfl_xor(pd, off, 64);
        float pos = pd * TEMP_INV;
        // this lane's two z_pred fragments (fixed across passes)
        const uint4* zl4 = reinterpret_cast<const uint4*>(zq[wid]);
        uint4 zs0 = zl4[s], zs1 = zl4[8 + s];

        float sl = 0.0f;
#pragma unroll
        for (int p = 0; p < 16; ++p) {
            int cur = p & 1, nxt = cur ^ 1;
            if (p < 15) {
                buf[nxt][0] = ni4[(size_t)idxp[p + 1] * 16 + s];
                buf[nxt][1] = ni4[(size_t)idxp[p + 1] * 16 + 8 + s];
            }
            uint4 g0 = buf[cur][0], g1 = buf[cur][1];
            int a0 = 0, a1 = 0;
            a0 = sdot4(g0.x, zs0.x, a0); a0 = sdot4(g0.y, zs0.y, a0);
            a0 = sdot4(g0.z, zs0.z, a0); a0 = sdot4(g0.w, zs0.w, a0);
            a1 = sdot4(g1.x, zs1.x, a1); a1 = sdot4(g1.y, zs1.y, a1);
            a1 = sdot4(g1.z, zs1.z, a1); a1 = sdot4(g1.w, zs1.w, a1);
            int acc = a0 + a1;
            acc += __shfl_xor(acc, 1, 64);
            acc += __shfl_xor(acc, 2, 64);
            acc += __shfl_xor(acc, 4, 64);
            sl += __expf((float)acc * QSCALE - FMAXL);
        }
        // butterfly over group-id bits only -> sums one copy per group
        sl += __shfl_xor(sl, 8, 64);
        sl += __shfl_xor(sl, 16, 64);
        sl += __shfl_xor(sl, 32, 64);
        float S = sl + __expf(pos - FMAXL);
        contrib = (FMAXL + __logf(S) - pos) * hp.scale;
    }
    if (lane == 0) partial[wid] = contrib;
    __syncthreads();
    if (threadIdx.x == 0)
        partials[blockIdx.y * GX + blockIdx.x] =
            partial[0] + partial[1] + partial[2] + partial[3];
}

// Single-block deterministic reduction of NPART partials -> out[0].
__global__ __launch_bounds__(256) void k_final(const float* __restrict__ partials,
                                               float* __restrict__ out) {
    __shared__ float ws[4];
    int wid = threadIdx.x >> 6, lane = threadIdx.x & 63;
    float s = 0.0f;
    for (int i = threadIdx.x; i < NPART; i += 256) s += partials[i];
#pragma unroll
    for (int off = 32; off; off >>= 1) s += __shfl_xor(s, off, 64);
    if (lane == 0) ws[wid] = s;
    __syncthreads();
    if (threadIdx.x == 0) out[0] = ws[0] + ws[1] + ws[2] + ws[3];
}

extern "C" void kernel_launch(void* const* d_in, const int* in_sizes, int n_in,
                              void* d_out, int out_size, void* d_ws, size_t ws_size,
                              hipStream_t stream) {
    const float* z     = (const float*)d_in[0];
    const float* preds = (const float*)d_in[1];
    const int*   nidx  = (const int*)d_in[2];
    float* out = (float*)d_out;

    unsigned* az   = (unsigned*)d_ws;                                // 4 MB
    unsigned* ani  = (unsigned*)((char*)d_ws + (size_t)4194304);     // 2 MB
    unsigned* Wh   = (unsigned*)((char*)d_ws + (size_t)6291456);     // 384 KB
    _Float16* zp   = (_Float16*)((char*)d_ws + (size_t)6684672);     // 12 MB
    float*    part = (float*)((char*)d_ws + (size_t)19267584);       // 24 KB

    const int ks[3] = {1, 5, 21};
    double rw[3] = {1.0, 1.0 / sqrt(5.0), 1.0 / sqrt(21.0)};
    double tot = rw[0] + rw[1] + rw[2];

    HP3 P;
    for (int i = 0; i < 3; ++i) {
        int L = Tc - ks[i], N = Bc * L;
        P.h[i].L = L; P.h[i].N = N; P.h[i].kh = ks[i];
        P.h[i].scale = (float)(rw[i] / tot / (double)N);
        P.h[i].nxOff = (long long)i * BTc * NNEGc;
    }

    k_norm<<<BTc / 4, 256, 0, stream>>>(z, preds, az, ani, Wh);
    k_gemm<<<dim3(BTc / 64, (3 * Dc) / 64), 256, 0, stream>>>(az, Wh, zp);
    k_loss<<<dim3(GX, 3), 256, 0, stream>>>(az, ani, zp, nidx, part, P);
    k_final<<<1, 256, 0, stream>>>(part, out);
}

// Round 15
// 108.848 us; speedup vs baseline: 1.2352x; 1.0759x over previous
//
#include <hip/hip_runtime.h>
#include <math.h>

// CPC loss, MI355X. B=16 T=512 D=256, horizons {1,5,21}, 128 negatives, temp 0.07.
// ws: [0,4MB) az f16 | [4MB,+1MB) ani4 int4 | [5MB,+384KB) Wh f16 |
//     [5.375MB,+12MB) zp f16 | [17.375MB,+24KB) partials f32
constexpr int Bc = 16, Tc = 512, Dc = 256, NNEGc = 128, BTc = Bc * Tc;
constexpr float TEMP_INV = 1.0f / 0.07f;
constexpr float SCALE4 = 21.875f;              // 7 / 0.32 clip
constexpr float QSCALE4 = TEMP_INV / (SCALE4 * SCALE4);
constexpr float FMAXL = TEMP_INV;              // algebraic softmax stabilizer
constexpr int GX = 2043;                       // ceil(8176/4)
constexpr int NPART = 3 * GX;

typedef __attribute__((ext_vector_type(8))) short short8;
typedef __attribute__((ext_vector_type(4))) float f32x4;
typedef __attribute__((ext_vector_type(4))) _Float16 f16x4;
typedef __attribute__((ext_vector_type(2))) _Float16 h2;

struct HP { int L, N, kh; float scale; long long nxOff; };
struct HP3 { HP h[3]; };

__device__ inline unsigned packh2(float a, float b) {
    h2 p = {(_Float16)a, (_Float16)b};
    return __builtin_bit_cast(unsigned, p);
}
__device__ inline float dot2(unsigned a, unsigned b, float c) {
#if __has_builtin(__builtin_amdgcn_fdot2)
    return __builtin_amdgcn_fdot2(__builtin_bit_cast(h2, a), __builtin_bit_cast(h2, b), c, false);
#else
    h2 x = __builtin_bit_cast(h2, a), y = __builtin_bit_cast(h2, b);
    return c + (float)x.x * (float)y.x + (float)x.y * (float)y.y;
#endif
}
__device__ inline int sdot8(unsigned a, unsigned b, int c) {
#if __has_builtin(__builtin_amdgcn_sdot8)
    return __builtin_amdgcn_sdot8((int)a, (int)b, c, false);
#else
#pragma unroll
    for (int i = 0; i < 8; ++i) {
        int xa = ((int)(a << (28 - 4 * i))) >> 28;
        int xb = ((int)(b << (28 - 4 * i))) >> 28;
        c += xa * xb;
    }
    return c;
#endif
}
// 4 floats -> 4 signed int4 nibbles (clipped to +-7), packed low-nibble-first
__device__ inline unsigned q4x4(float a, float b, float c, float d) {
    int qa = (int)rintf(fminf(fmaxf(a * SCALE4, -7.0f), 7.0f));
    int qb = (int)rintf(fminf(fmaxf(b * SCALE4, -7.0f), 7.0f));
    int qc = (int)rintf(fminf(fmaxf(c * SCALE4, -7.0f), 7.0f));
    int qd = (int)rintf(fminf(fmaxf(d * SCALE4, -7.0f), 7.0f));
    return (qa & 0xF) | ((qb & 0xF) << 4) | ((qc & 0xF) << 8) | ((qd & 0xF) << 12);
}

// Normalize all BT rows -> az (f16, 512 B/row) + ani4 (int4, 128 B/row);
// first 96 blocks convert W to f16.
__global__ __launch_bounds__(256) void k_norm(const float* __restrict__ z,
                                              const float* __restrict__ preds,
                                              unsigned* __restrict__ az,
                                              unsigned short* __restrict__ ani4,
                                              unsigned* __restrict__ Wh) {
    if (blockIdx.x < 96) {
        int base = blockIdx.x * 2048 + threadIdx.x * 8;
        float4 w0 = reinterpret_cast<const float4*>(preds + base)[0];
        float4 w1 = reinterpret_cast<const float4*>(preds + base)[1];
        uint4 o;
        o.x = packh2(w0.x, w0.y); o.y = packh2(w0.z, w0.w);
        o.z = packh2(w1.x, w1.y); o.w = packh2(w1.z, w1.w);
        reinterpret_cast<uint4*>(Wh)[blockIdx.x * 256 + threadIdx.x] = o;
    }
    int wid = threadIdx.x >> 6, lane = threadIdx.x & 63;
    int row = blockIdx.x * 4 + wid;
    float4 v = reinterpret_cast<const float4*>(z)[row * 64 + lane];
    float s = v.x * v.x + v.y * v.y + v.z * v.z + v.w * v.w;
#pragma unroll
    for (int off = 32; off; off >>= 1) s += __shfl_xor(s, off, 64);
    float inv = 1.0f / fmaxf(sqrtf(s), 1e-12f);
    float a = v.x * inv, b = v.y * inv, c = v.z * inv, d = v.w * inv;
    reinterpret_cast<uint2*>(az)[row * 64 + lane] = make_uint2(packh2(a, b), packh2(c, d));
    // int4 row: lane l holds elements 4l..4l+3 -> nibbles 4l..4l+3 (ushort l)
    ani4[row * 64 + lane] = (unsigned short)q4x4(a, b, c, d);
}

// LDS-tiled f16 MFMA GEMM, XOR-swizzled LDS. Block 64x64, K=256, 4 waves.
__global__ __launch_bounds__(256) void k_gemm(const unsigned* __restrict__ az,
                                              const unsigned* __restrict__ Wh,
                                              _Float16* __restrict__ zp) {
    __shared__ uint4 As[2048];
    __shared__ uint4 Bs[2048];
    int wave = threadIdx.x >> 6, lane = threadIdx.x & 63;
    int t = threadIdx.x;
    int m0 = blockIdx.x * 64, g0 = blockIdx.y * 64;
    const uint4* A4 = reinterpret_cast<const uint4*>(az) + (size_t)m0 * 32;
    const uint4* B4 = reinterpret_cast<const uint4*>(Wh) + (size_t)g0 * 32;
#pragma unroll
    for (int i = 0; i < 8; ++i) {
        int f = i * 256 + t;
        int r = f >> 5, c = f & 31;
        int sw = r * 32 + ((c ^ r) & 31);
        As[sw] = A4[f];
        Bs[sw] = B4[f];
    }
    __syncthreads();
    int mrow = lane & 15, kq = lane >> 4;
    f32x4 acc[4] = {f32x4{0,0,0,0}, f32x4{0,0,0,0}, f32x4{0,0,0,0}, f32x4{0,0,0,0}};
    int arow = wave * 16 + mrow;
#pragma unroll
    for (int kb = 0; kb < 8; ++kb) {
        int col = kb * 4 + kq;
        uint4 ua = As[arow * 32 + ((col ^ arow) & 31)];
        short8 a = __builtin_bit_cast(short8, ua);
#pragma unroll
        for (int nt = 0; nt < 4; ++nt) {
            int brow = nt * 16 + mrow;
            uint4 ub = Bs[brow * 32 + ((col ^ brow) & 31)];
            acc[nt] = __builtin_amdgcn_mfma_f32_16x16x32_f16(
                a, __builtin_bit_cast(short8, ub), acc[nt], 0, 0, 0);
        }
    }
#pragma unroll
    for (int nt = 0; nt < 4; ++nt) {
        int g = g0 + nt * 16 + mrow;
        int h = g >> 8, e = g & 255;
        _Float16* dst = zp + ((size_t)h * BTc + m0 + wave * 16 + kq * 4) * Dc + e;
#pragma unroll
        for (int r = 0; r < 4; ++r) dst[(size_t)r * Dc] = (_Float16)acc[nt][r];
    }
}

// One wave per row n. INT4 8-lane-per-negative gather: one instr = 8 FULL
// negative rows (128 B each, fully consumed) -> 16 gather instrs/wave (half of
// int8). sdot8 dots, fixed-max softmax, cross-group butterfly (one rep per
// group, no division). Per-block partial store.
__global__ __launch_bounds__(256, 4) void k_loss(const unsigned* __restrict__ az,
                                                 const unsigned* __restrict__ ani4,
                                                 const _Float16* __restrict__ zp_base,
                                                 const int* __restrict__ nx_base,
                                                 float* __restrict__ partials,
                                                 HP3 P) {
    HP hp = P.h[blockIdx.y];
    __shared__ uint4 zqm[4][8];      // per-wave int4 z_pred row (128 B)
    __shared__ float partial[4];
    int wid = threadIdx.x >> 6, lane = threadIdx.x & 63;
    int g = lane >> 3, s = lane & 7;
    int n = blockIdx.x * 4 + wid;
    float contrib = 0.0f;
    if (n < hp.N) {
        const int* nx = nx_base + hp.nxOff + (size_t)n * NNEGc;
        int i1 = nx[lane], i2 = nx[lane + 64];
        // pass p, group g -> negative p*8+g
        int idxp[16];
#pragma unroll
        for (int p = 0; p < 16; ++p)
            idxp[p] = __shfl(p < 8 ? i1 : i2, (p & 7) * 8 + g, 64);

        const uint4* ni4 = reinterpret_cast<const uint4*>(ani4);
        uint4 buf[2];
        buf[0] = ni4[(size_t)idxp[0] * 8 + s];

        // setup rides under the first prefetch
        int b = n / hp.L, l = n - b * hp.L;
        int row = b * Tc + l;
        f16x4 hv = reinterpret_cast<const f16x4*>(
                       zp_base + ((size_t)blockIdx.y * BTc + row) * Dc)[lane];
        uint2 pw = reinterpret_cast<const uint2*>(az + (size_t)(row + hp.kh) * 128)[lane];
        float4 v = make_float4((float)hv.x, (float)hv.y, (float)hv.z, (float)hv.w);
        float sq = v.x * v.x + v.y * v.y + v.z * v.z + v.w * v.w;
#pragma unroll
        for (int off = 32; off; off >>= 1) sq += __shfl_xor(sq, off, 64);
        float inv = 1.0f / fmaxf(sqrtf(sq), 1e-12f);
        v.x *= inv; v.y *= inv; v.z *= inv; v.w *= inv;
        // int4 z_pred: lane l -> elements 4l..4l+3 (ushort l of the 128 B row)
        reinterpret_cast<unsigned short*>(zqm[wid])[lane] =
            (unsigned short)q4x4(v.x, v.y, v.z, v.w);
        float pd = dot2(pw.y, packh2(v.z, v.w), dot2(pw.x, packh2(v.x, v.y), 0.0f));
#pragma unroll
        for (int off = 32; off; off >>= 1) pd += __shfl_xor(pd, off, 64);
        float pos = pd * TEMP_INV;
        // this lane's 32-element int4 slice (elements s*32..s*32+31)
        uint4 zs = zqm[wid][s];

        float sl = 0.0f;
#pragma unroll
        for (int p = 0; p < 16; ++p) {
            int cur = p & 1, nxt = cur ^ 1;
            if (p < 15) buf[nxt] = ni4[(size_t)idxp[p + 1] * 8 + s];
            uint4 gl = buf[cur];
            int acc = 0;
            acc = sdot8(gl.x, zs.x, acc);
            acc = sdot8(gl.y, zs.y, acc);
            acc = sdot8(gl.z, zs.z, acc);
            acc = sdot8(gl.w, zs.w, acc);
            acc += __shfl_xor(acc, 1, 64);
            acc += __shfl_xor(acc, 2, 64);
            acc += __shfl_xor(acc, 4, 64);
            sl += __expf((float)acc * QSCALE4 - FMAXL);
        }
        // butterfly over group-id bits -> sums one copy per group (no division)
        sl += __shfl_xor(sl, 8, 64);
        sl += __shfl_xor(sl, 16, 64);
        sl += __shfl_xor(sl, 32, 64);
        float S = sl + __expf(pos - FMAXL);
        contrib = (FMAXL + __logf(S) - pos) * hp.scale;
    }
    if (lane == 0) partial[wid] = contrib;
    __syncthreads();
    if (threadIdx.x == 0)
        partials[blockIdx.y * GX + blockIdx.x] =
            partial[0] + partial[1] + partial[2] + partial[3];
}

// Single-block deterministic reduction of NPART partials -> out[0].
__global__ __launch_bounds__(256) void k_final(const float* __restrict__ partials,
                                               float* __restrict__ out) {
    __shared__ float ws[4];
    int wid = threadIdx.x >> 6, lane = threadIdx.x & 63;
    float s = 0.0f;
    for (int i = threadIdx.x; i < NPART; i += 256) s += partials[i];
#pragma unroll
    for (int off = 32; off; off >>= 1) s += __shfl_xor(s, off, 64);
    if (lane == 0) ws[wid] = s;
    __syncthreads();
    if (threadIdx.x == 0) out[0] = ws[0] + ws[1] + ws[2] + ws[3];
}

extern "C" void kernel_launch(void* const* d_in, const int* in_sizes, int n_in,
                              void* d_out, int out_size, void* d_ws, size_t ws_size,
                              hipStream_t stream) {
    const float* z     = (const float*)d_in[0];
    const float* preds = (const float*)d_in[1];
    const int*   nidx  = (const int*)d_in[2];
    float* out = (float*)d_out;

    unsigned*       az   = (unsigned*)d_ws;                                  // 4 MB
    unsigned short* ani4 = (unsigned short*)((char*)d_ws + (size_t)4194304); // 1 MB
    unsigned*       Wh   = (unsigned*)((char*)d_ws + (size_t)5242880);       // 384 KB
    _Float16*       zp   = (_Float16*)((char*)d_ws + (size_t)5636096);       // 12 MB
    float*          part = (float*)((char*)d_ws + (size_t)18219008);         // 24 KB

    const int ks[3] = {1, 5, 21};
    double rw[3] = {1.0, 1.0 / sqrt(5.0), 1.0 / sqrt(21.0)};
    double tot = rw[0] + rw[1] + rw[2];

    HP3 P;
    for (int i = 0; i < 3; ++i) {
        int L = Tc - ks[i], N = Bc * L;
        P.h[i].L = L; P.h[i].N = N; P.h[i].kh = ks[i];
        P.h[i].scale = (float)(rw[i] / tot / (double)N);
        P.h[i].nxOff = (long long)i * BTc * NNEGc;
    }

    k_norm<<<BTc / 4, 256, 0, stream>>>(z, preds, az, ani4, Wh);
    k_gemm<<<dim3(BTc / 64, (3 * Dc) / 64), 256, 0, stream>>>(az, Wh, zp);
    k_loss<<<dim3(GX, 3), 256, 0, stream>>>(az, (const unsigned*)ani4, zp, nidx, part, P);
    k_final<<<1, 256, 0, stream>>>(part, out);
}

// Round 16
// 105.240 us; speedup vs baseline: 1.2776x; 1.0343x over previous
//
#include <hip/hip_runtime.h>
#include <math.h>

// CPC loss, MI355X. B=16 T=512 D=256, horizons {1,5,21}, 128 negatives, temp 0.07.
// ws: [0,4MB) az f16 | [4MB,+1MB) ani4 int4 | [5MB,+384KB) Wh f16 |
//     [5.375MB,+12MB) zp f16 | [17.375MB,+24KB) partials f32
constexpr int Bc = 16, Tc = 512, Dc = 256, NNEGc = 128, BTc = Bc * Tc;
constexpr float TEMP_INV = 1.0f / 0.07f;
constexpr float SCALE4 = 21.875f;              // 7 / 0.32 clip
constexpr float QSCALE4 = TEMP_INV / (SCALE4 * SCALE4);
constexpr float FMAXL = TEMP_INV;              // algebraic softmax stabilizer
constexpr int GX = 2043;                       // ceil(8176/4)
constexpr int NPART = 3 * GX;

typedef __attribute__((ext_vector_type(8))) short short8;
typedef __attribute__((ext_vector_type(4))) float f32x4;
typedef __attribute__((ext_vector_type(4))) _Float16 f16x4;
typedef __attribute__((ext_vector_type(2))) _Float16 h2;

struct HP { int L, N, kh; float scale; long long nxOff; };
struct HP3 { HP h[3]; };

__device__ inline unsigned packh2(float a, float b) {
    h2 p = {(_Float16)a, (_Float16)b};
    return __builtin_bit_cast(unsigned, p);
}
__device__ inline float dot2(unsigned a, unsigned b, float c) {
#if __has_builtin(__builtin_amdgcn_fdot2)
    return __builtin_amdgcn_fdot2(__builtin_bit_cast(h2, a), __builtin_bit_cast(h2, b), c, false);
#else
    h2 x = __builtin_bit_cast(h2, a), y = __builtin_bit_cast(h2, b);
    return c + (float)x.x * (float)y.x + (float)x.y * (float)y.y;
#endif
}
__device__ inline int sdot8(unsigned a, unsigned b, int c) {
#if __has_builtin(__builtin_amdgcn_sdot8)
    return __builtin_amdgcn_sdot8((int)a, (int)b, c, false);
#else
#pragma unroll
    for (int i = 0; i < 8; ++i) {
        int xa = ((int)(a << (28 - 4 * i))) >> 28;
        int xb = ((int)(b << (28 - 4 * i))) >> 28;
        c += xa * xb;
    }
    return c;
#endif
}
// 4 floats -> 4 signed int4 nibbles (clipped to +-7), packed low-nibble-first
__device__ inline unsigned q4x4(float a, float b, float c, float d) {
    int qa = (int)rintf(fminf(fmaxf(a * SCALE4, -7.0f), 7.0f));
    int qb = (int)rintf(fminf(fmaxf(b * SCALE4, -7.0f), 7.0f));
    int qc = (int)rintf(fminf(fmaxf(c * SCALE4, -7.0f), 7.0f));
    int qd = (int)rintf(fminf(fmaxf(d * SCALE4, -7.0f), 7.0f));
    return (qa & 0xF) | ((qb & 0xF) << 4) | ((qc & 0xF) << 8) | ((qd & 0xF) << 12);
}

// Normalize all BT rows -> az (f16, 512 B/row) + ani4 (int4, 128 B/row);
// first 96 blocks convert W to f16.
__global__ __launch_bounds__(256) void k_norm(const float* __restrict__ z,
                                              const float* __restrict__ preds,
                                              unsigned* __restrict__ az,
                                              unsigned short* __restrict__ ani4,
                                              unsigned* __restrict__ Wh) {
    if (blockIdx.x < 96) {
        int base = blockIdx.x * 2048 + threadIdx.x * 8;
        float4 w0 = reinterpret_cast<const float4*>(preds + base)[0];
        float4 w1 = reinterpret_cast<const float4*>(preds + base)[1];
        uint4 o;
        o.x = packh2(w0.x, w0.y); o.y = packh2(w0.z, w0.w);
        o.z = packh2(w1.x, w1.y); o.w = packh2(w1.z, w1.w);
        reinterpret_cast<uint4*>(Wh)[blockIdx.x * 256 + threadIdx.x] = o;
    }
    int wid = threadIdx.x >> 6, lane = threadIdx.x & 63;
    int row = blockIdx.x * 4 + wid;
    float4 v = reinterpret_cast<const float4*>(z)[row * 64 + lane];
    float s = v.x * v.x + v.y * v.y + v.z * v.z + v.w * v.w;
#pragma unroll
    for (int off = 32; off; off >>= 1) s += __shfl_xor(s, off, 64);
    float inv = 1.0f / fmaxf(sqrtf(s), 1e-12f);
    float a = v.x * inv, b = v.y * inv, c = v.z * inv, d = v.w * inv;
    reinterpret_cast<uint2*>(az)[row * 64 + lane] = make_uint2(packh2(a, b), packh2(c, d));
    ani4[row * 64 + lane] = (unsigned short)q4x4(a, b, c, d);
}

// LDS-tiled f16 MFMA GEMM, XOR-swizzled LDS. Block 64x64, K=256, 4 waves.
__global__ __launch_bounds__(256) void k_gemm(const unsigned* __restrict__ az,
                                              const unsigned* __restrict__ Wh,
                                              _Float16* __restrict__ zp) {
    __shared__ uint4 As[2048];
    __shared__ uint4 Bs[2048];
    int wave = threadIdx.x >> 6, lane = threadIdx.x & 63;
    int t = threadIdx.x;
    int m0 = blockIdx.x * 64, g0 = blockIdx.y * 64;
    const uint4* A4 = reinterpret_cast<const uint4*>(az) + (size_t)m0 * 32;
    const uint4* B4 = reinterpret_cast<const uint4*>(Wh) + (size_t)g0 * 32;
#pragma unroll
    for (int i = 0; i < 8; ++i) {
        int f = i * 256 + t;
        int r = f >> 5, c = f & 31;
        int sw = r * 32 + ((c ^ r) & 31);
        As[sw] = A4[f];
        Bs[sw] = B4[f];
    }
    __syncthreads();
    int mrow = lane & 15, kq = lane >> 4;
    f32x4 acc[4] = {f32x4{0,0,0,0}, f32x4{0,0,0,0}, f32x4{0,0,0,0}, f32x4{0,0,0,0}};
    int arow = wave * 16 + mrow;
#pragma unroll
    for (int kb = 0; kb < 8; ++kb) {
        int col = kb * 4 + kq;
        uint4 ua = As[arow * 32 + ((col ^ arow) & 31)];
        short8 a = __builtin_bit_cast(short8, ua);
#pragma unroll
        for (int nt = 0; nt < 4; ++nt) {
            int brow = nt * 16 + mrow;
            uint4 ub = Bs[brow * 32 + ((col ^ brow) & 31)];
            acc[nt] = __builtin_amdgcn_mfma_f32_16x16x32_f16(
                a, __builtin_bit_cast(short8, ub), acc[nt], 0, 0, 0);
        }
    }
#pragma unroll
    for (int nt = 0; nt < 4; ++nt) {
        int g = g0 + nt * 16 + mrow;
        int h = g >> 8, e = g & 255;
        _Float16* dst = zp + ((size_t)h * BTc + m0 + wave * 16 + kq * 4) * Dc + e;
#pragma unroll
        for (int r = 0; r < 4; ++r) dst[(size_t)r * Dc] = (_Float16)acc[nt][r];
    }
}

// One wave per row n. INT4 8-lane-per-negative gather (16 gather instrs/wave =
// the hard minimum: 16 KB at 1 KB/instr). PACKED DUAL-PASS BUTTERFLY: two
// negatives' biased partial dots share one 32-bit word (per-lane field
// [480,3616]; 8-lane sum <= 28928 < 2^16 -> carry-free, integer-exact), so one
// 3-shuffle butterfly reduces two passes (48 -> 24 shuffles/wave). Indices
// recomputed in-loop (frees 16 VGPRs). Fixed-max softmax; partial store.
__global__ __launch_bounds__(256, 4) void k_loss(const unsigned* __restrict__ az,
                                                 const unsigned* __restrict__ ani4,
                                                 const _Float16* __restrict__ zp_base,
                                                 const int* __restrict__ nx_base,
                                                 float* __restrict__ partials,
                                                 HP3 P) {
    HP hp = P.h[blockIdx.y];
    __shared__ uint4 zqm[4][8];      // per-wave int4 z_pred row (128 B)
    __shared__ float partial[4];
    int wid = threadIdx.x >> 6, lane = threadIdx.x & 63;
    int g = lane >> 3, s = lane & 7;
    int n = blockIdx.x * 4 + wid;
    float contrib = 0.0f;
    if (n < hp.N) {
        const int* nx = nx_base + hp.nxOff + (size_t)n * NNEGc;
        int i1 = nx[lane], i2 = nx[lane + 64];
        const uint4* ni4 = reinterpret_cast<const uint4*>(ani4);
        // pass p (0..15), group g -> negative (p&7)*8+g from half p>>3
        int ia = __shfl(i1, 0 * 8 + g, 64);
        int ib = __shfl(i1, 1 * 8 + g, 64);
        uint4 buf[2][2];
        buf[0][0] = ni4[(size_t)ia * 8 + s];
        buf[0][1] = ni4[(size_t)ib * 8 + s];

        // setup rides under the first prefetch
        int b = n / hp.L, l = n - b * hp.L;
        int row = b * Tc + l;
        f16x4 hv = reinterpret_cast<const f16x4*>(
                       zp_base + ((size_t)blockIdx.y * BTc + row) * Dc)[lane];
        uint2 pw = reinterpret_cast<const uint2*>(az + (size_t)(row + hp.kh) * 128)[lane];
        float4 v = make_float4((float)hv.x, (float)hv.y, (float)hv.z, (float)hv.w);
        float sq = v.x * v.x + v.y * v.y + v.z * v.z + v.w * v.w;
#pragma unroll
        for (int off = 32; off; off >>= 1) sq += __shfl_xor(sq, off, 64);
        float inv = 1.0f / fmaxf(sqrtf(sq), 1e-12f);
        v.x *= inv; v.y *= inv; v.z *= inv; v.w *= inv;
        reinterpret_cast<unsigned short*>(zqm[wid])[lane] =
            (unsigned short)q4x4(v.x, v.y, v.z, v.w);
        float pd = dot2(pw.y, packh2(v.z, v.w), dot2(pw.x, packh2(v.x, v.y), 0.0f));
#pragma unroll
        for (int off = 32; off; off >>= 1) pd += __shfl_xor(pd, off, 64);
        float pos = pd * TEMP_INV;
        uint4 zs = zqm[wid][s];   // this lane's 32-element int4 slice

        float sl = 0.0f;
#pragma unroll
        for (int k = 0; k < 8; ++k) {   // double-pass k covers passes 2k, 2k+1
            int cur = k & 1, nxt = cur ^ 1;
            if (k < 7) {
                int p0 = 2 * k + 2, p1 = 2 * k + 3;
                int na = __shfl(p0 < 8 ? i1 : i2, (p0 & 7) * 8 + g, 64);
                int nb = __shfl(p1 < 8 ? i1 : i2, (p1 & 7) * 8 + g, 64);
                buf[nxt][0] = ni4[(size_t)na * 8 + s];
                buf[nxt][1] = ni4[(size_t)nb * 8 + s];
            }
            uint4 ga = buf[cur][0], gb = buf[cur][1];
            int aa = 0, ab = 0;
            aa = sdot8(ga.x, zs.x, aa); aa = sdot8(ga.y, zs.y, aa);
            aa = sdot8(ga.z, zs.z, aa); aa = sdot8(ga.w, zs.w, aa);
            ab = sdot8(gb.x, zs.x, ab); ab = sdot8(gb.y, zs.y, ab);
            ab = sdot8(gb.z, zs.z, ab); ab = sdot8(gb.w, zs.w, ab);
            // pack both biased partials; one butterfly reduces both (exact)
            unsigned pk = ((unsigned)(aa + 2048) << 16) | (unsigned)(ab + 2048);
            pk += (unsigned)__shfl_xor((int)pk, 1, 64);
            pk += (unsigned)__shfl_xor((int)pk, 2, 64);
            pk += (unsigned)__shfl_xor((int)pk, 4, 64);
            float la = (float)((int)(pk >> 16) - 16384);
            float lb = (float)((int)(pk & 0xffffu) - 16384);
            sl += __expf(la * QSCALE4 - FMAXL) + __expf(lb * QSCALE4 - FMAXL);
        }
        // butterfly over group-id bits -> sums one copy per group (no division)
        sl += __shfl_xor(sl, 8, 64);
        sl += __shfl_xor(sl, 16, 64);
        sl += __shfl_xor(sl, 32, 64);
        float S = sl + __expf(pos - FMAXL);
        contrib = (FMAXL + __logf(S) - pos) * hp.scale;
    }
    if (lane == 0) partial[wid] = contrib;
    __syncthreads();
    if (threadIdx.x == 0)
        partials[blockIdx.y * GX + blockIdx.x] =
            partial[0] + partial[1] + partial[2] + partial[3];
}

// Single-block deterministic reduction of NPART partials -> out[0].
__global__ __launch_bounds__(256) void k_final(const float* __restrict__ partials,
                                               float* __restrict__ out) {
    __shared__ float ws[4];
    int wid = threadIdx.x >> 6, lane = threadIdx.x & 63;
    float s = 0.0f;
    for (int i = threadIdx.x; i < NPART; i += 256) s += partials[i];
#pragma unroll
    for (int off = 32; off; off >>= 1) s += __shfl_xor(s, off, 64);
    if (lane == 0) ws[wid] = s;
    __syncthreads();
    if (threadIdx.x == 0) out[0] = ws[0] + ws[1] + ws[2] + ws[3];
}

extern "C" void kernel_launch(void* const* d_in, const int* in_sizes, int n_in,
                              void* d_out, int out_size, void* d_ws, size_t ws_size,
                              hipStream_t stream) {
    const float* z     = (const float*)d_in[0];
    const float* preds = (const float*)d_in[1];
    const int*   nidx  = (const int*)d_in[2];
    float* out = (float*)d_out;

    unsigned*       az   = (unsigned*)d_ws;                                  // 4 MB
    unsigned short* ani4 = (unsigned short*)((char*)d_ws + (size_t)4194304); // 1 MB
    unsigned*       Wh   = (unsigned*)((char*)d_ws + (size_t)5242880);       // 384 KB
    _Float16*       zp   = (_Float16*)((char*)d_ws + (size_t)5636096);       // 12 MB
    float*          part = (float*)((char*)d_ws + (size_t)18219008);         // 24 KB

    const int ks[3] = {1, 5, 21};
    double rw[3] = {1.0, 1.0 / sqrt(5.0), 1.0 / sqrt(21.0)};
    double tot = rw[0] + rw[1] + rw[2];

    HP3 P;
    for (int i = 0; i < 3; ++i) {
        int L = Tc - ks[i], N = Bc * L;
        P.h[i].L = L; P.h[i].N = N; P.h[i].kh = ks[i];
        P.h[i].scale = (float)(rw[i] / tot / (double)N);
        P.h[i].nxOff = (long long)i * BTc * NNEGc;
    }

    k_norm<<<BTc / 4, 256, 0, stream>>>(z, preds, az, ani4, Wh);
    k_gemm<<<dim3(BTc / 64, (3 * Dc) / 64), 256, 0, stream>>>(az, Wh, zp);
    k_loss<<<dim3(GX, 3), 256, 0, stream>>>(az, (const unsigned*)ani4, zp, nidx, part, P);
    k_final<<<1, 256, 0, stream>>>(part, out);
}